// Round 1
// 282.126 us; speedup vs baseline: 1.0265x; 1.0265x over previous
//
#include <hip/hip_runtime.h>
#include <hip/hip_bf16.h>
#include <math.h>

typedef __attribute__((ext_vector_type(8))) short short8;
typedef __attribute__((ext_vector_type(4))) float floatx4;
typedef __attribute__((ext_vector_type(4))) unsigned int uintx4;
typedef __attribute__((ext_vector_type(2))) unsigned int uintx2;

__device__ __forceinline__ unsigned short f2bf(float f) {
    unsigned int u = __float_as_uint(f);
    unsigned int r = (u + 0x7fffu + ((u >> 16) & 1u)) >> 16;
    return (unsigned short)r;
}

// single-instruction RNE pack: low16 <- a, high16 <- b
__device__ __forceinline__ unsigned int cvtpk(float a, float b) {
    unsigned int r;
    asm("v_cvt_pk_bf16_f32 %0, %1, %2" : "=v"(r) : "v"(a), "v"(b));
    return r;
}

// gelu(u) = u * sigmoid(1.5957691216*u*(1+0.044715*u^2))
// log2e folded: z = -(k1 + k3*u^2)*u, e = 2^z
__device__ __forceinline__ float gelu_f(float u) {
    float u2 = u * u;
    float p = __builtin_fmaf(u2, -0.102943242f, -2.302208184f);
    float z = p * u;
    float e;
    asm("v_exp_f32 %0, %1" : "=v"(e) : "v"(z));
    return u * __builtin_amdgcn_rcpf(1.0f + e);
}

__device__ __forceinline__ floatx4 mfma16(short8 a, short8 b, floatx4 c) {
    return __builtin_amdgcn_mfma_f32_16x16x32_bf16(a, b, c, 0, 0, 0);
}

// ---------------- Phase A ----------------

// 512 blocks: deterministic partial |W| sums (16 partials per tile)
__global__ __launch_bounds__(256) void k_sumabs(const float* __restrict__ W1,
                                                const float* __restrict__ W2,
                                                float* __restrict__ partials) {
    int blk = blockIdx.x;
    bool isW1 = blk < 256;
    const float* W = (isW1 ? W1 : W2) + (long)(isW1 ? blk : blk - 256) * 4096;
    float s = 0.f;
    #pragma unroll
    for (int i = 0; i < 4; i++) {
        floatx4 v = *(const floatx4*)(W + i * 1024 + threadIdx.x * 4);
        s += fabsf(v[0]) + fabsf(v[1]) + fabsf(v[2]) + fabsf(v[3]);
    }
    __shared__ float red[256];
    red[threadIdx.x] = s; __syncthreads();
    for (int st = 128; st > 0; st >>= 1) {
        if (threadIdx.x < st) red[threadIdx.x] += red[threadIdx.x + st];
        __syncthreads();
    }
    if (threadIdx.x == 0) partials[blk] = red[0];
}

// 512 blocks x 256 threads x 16 elems; deterministic s from partials
__global__ __launch_bounds__(256) void k_quant(
        const float* __restrict__ W1, const float* __restrict__ W2,
        const float* __restrict__ partials,
        unsigned short* __restrict__ W1qT, unsigned short* __restrict__ W2qT,
        float* ternsum) {
    int blk = blockIdx.x;
    bool isW1 = blk < 256;
    long el0 = (long)(isW1 ? blk : blk - 256) * 4096;
    int t = (int)(el0 >> 16);
    const float* part = partials + (isW1 ? 0 : 256) + t * 16;
    float ssum = 0.f;
    #pragma unroll
    for (int i = 0; i < 16; i++) ssum += part[i];
    float s = ssum * (1.0f / 65536.0f);
    float thr = 0.7f * s;
    unsigned int us = (unsigned int)f2bf(s);   // bf16(+s); bf16(-s) = us|0x8000
    const float* Wsrc = (isW1 ? W1 : W2) + el0;
    unsigned short* dst = (isW1 ? W1qT : W2qT) + (long)t * 65536;
    int locbase = (int)(el0 & 65535);
    float dsum = 0.f;
    #pragma unroll
    for (int i = 0; i < 4; i++) {
        int off = i * 1024 + threadIdx.x * 4;
        floatx4 w = *(const floatx4*)(Wsrc + off);
        int loc = locbase + off;
        #pragma unroll
        for (int r = 0; r < 4; r++) {
            float wv = w[r];
            float aw = fabsf(wv);
            bool big = aw > thr;
            dsum += big ? fabsf(aw - s) : aw;
            unsigned int sign15 = (__float_as_uint(wv) >> 16) & 0x8000u;
            unsigned short q = big ? (unsigned short)(us | sign15) : (unsigned short)0;
            int lr = loc + r;
            int addr = isW1 ? ((lr & 511) * 128 + (lr >> 9))
                            : ((lr & 127) * 512 + (lr >> 7));
            dst[addr] = q;
        }
    }
    __shared__ float red[256];
    red[threadIdx.x] = dsum; __syncthreads();
    for (int st2 = 128; st2 > 0; st2 >>= 1) {
        if (threadIdx.x < st2) red[threadIdx.x] += red[threadIdx.x + st2];
        __syncthreads();
    }
    if (threadIdx.x == 0) atomicAdd(ternsum, red[0]);
}

// W23qT[t][h][k2] = (W2q[t] @ Wh1)^T, bf16
__global__ __launch_bounds__(256) void k_w23(
        const unsigned short* __restrict__ W2qT, const float* __restrict__ Wh1,
        unsigned short* __restrict__ W23qT) {
    int t = blockIdx.x >> 6, h = blockIdx.x & 63;
    __shared__ float wcol[128];
    if (threadIdx.x < 128) wcol[threadIdx.x] = Wh1[threadIdx.x * 64 + h];
    __syncthreads();
    int k2 = threadIdx.x * 2;
    const unsigned short* w2 = W2qT + (long)t * 65536 + k2;
    float a0 = 0.f, a1 = 0.f;
    #pragma unroll 8
    for (int d = 0; d < 128; d++) {
        unsigned int u = *(const unsigned int*)(w2 + d * 512);
        float w = wcol[d];
        a0 += w * __uint_as_float(u << 16);
        a1 += w * __uint_as_float(u & 0xffff0000u);
    }
    *(unsigned int*)(W23qT + ((long)(t * 64 + h)) * 512 + k2) = cvtpk(a0, a1);
}

__global__ void k_tables(const float* __restrict__ op_embed, const float* __restrict__ W_in,
                         const float* __restrict__ b_in,
                         float* embW, float* Ta, float* Tb, float* Tc) {
    int i = blockIdx.x * 256 + threadIdx.x;
    if (i < 1024) {
        int op = i >> 7, j = i & 127;
        float s = b_in[j];
        #pragma unroll
        for (int k = 0; k < 32; k++) s += op_embed[op * 32 + k] * W_in[k * 128 + j];
        embW[i] = s;
    } else if (i < 1024 + 32768) {
        int r = i - 1024; int a = r >> 7, j = r & 127;
        float s = 0.f;
        #pragma unroll
        for (int bit = 0; bit < 8; bit++) if ((a >> bit) & 1) s += W_in[(32 + bit) * 128 + j];
        Ta[r] = s;
    } else if (i < 33792 + 32768) {
        int r = i - 33792; int b = r >> 7, j = r & 127;
        float s = 0.f;
        #pragma unroll
        for (int bit = 0; bit < 8; bit++) if ((b >> bit) & 1) s += W_in[(40 + bit) * 128 + j];
        Tb[r] = s;
    } else if (i < 66560 + 128) {
        int j = i - 66560; Tc[j] = W_in[48 * 128 + j];
    }
}

__global__ void k_tablesR(const float* __restrict__ embW, const float* __restrict__ Ta,
                          const float* __restrict__ Tb, const float* __restrict__ Tc,
                          const float* __restrict__ Wr,
                          float* embWr, float* TaR, float* TbR, float* TcR) {
    int i = blockIdx.x * 256 + threadIdx.x;
    int row = i >> 4, t = i & 15;
    const float* src; float* dst;
    if (row < 8)        { src = embW + row * 128;        dst = embWr + i; }
    else if (row < 264) { src = Ta + (row - 8) * 128;    dst = TaR + (row - 8) * 16 + t; }
    else if (row < 520) { src = Tb + (row - 264) * 128;  dst = TbR + (row - 264) * 16 + t; }
    else if (row == 520){ src = Tc;                      dst = TcR + t; }
    else return;
    float s = 0.f;
    for (int j = 0; j < 128; j++) s += src[j] * Wr[j * 16 + t];
    *dst = s;
}

// ---------------- Phase B: router + x ----------------

__global__ __launch_bounds__(256) void k_front(
        const int* __restrict__ op_idx, const int* __restrict__ a_in,
        const int* __restrict__ b_in_i, const int* __restrict__ c_in,
        const float* __restrict__ embW, const float* __restrict__ Ta,
        const float* __restrict__ Tb, const float* __restrict__ Tc,
        const float* __restrict__ embWr, const float* __restrict__ TaR,
        const float* __restrict__ TbR, const float* __restrict__ TcR,
        unsigned short* __restrict__ xq, float* __restrict__ gate_out,
        float* psum, int* cnt, float* __restrict__ d_idx) {
    __shared__ float sp[4][16];
    __shared__ int sc[4][16];
    int gid = blockIdx.x * 256 + threadIdx.x;
    int lane = threadIdx.x & 63;
    int j = lane & 15;
    int grpbase = lane & 48;
    float psum_acc = 0.f; int cnt_acc = 0;

    #pragma unroll 1
    for (int it = 0; it < 16; it++) {
        int tok = it * 16384 + (gid >> 4);
        int op = op_idx[tok], a = a_in[tok], b = b_in_i[tok], c = c_in[tok];
        float cf = (float)c;

        float lg = embWr[op * 16 + j] + TaR[a * 16 + j] + TbR[b * 16 + j] + cf * TcR[j];
        float m = lg;
        m = fmaxf(m, __shfl_xor(m, 8, 16));
        m = fmaxf(m, __shfl_xor(m, 4, 16));
        m = fmaxf(m, __shfl_xor(m, 2, 16));
        m = fmaxf(m, __shfl_xor(m, 1, 16));
        float p = __expf(lg - m);
        float s = p;
        s += __shfl_xor(s, 8, 16);
        s += __shfl_xor(s, 4, 16);
        s += __shfl_xor(s, 2, 16);
        s += __shfl_xor(s, 1, 16);
        float g = __builtin_amdgcn_rcpf(s);
        unsigned long long ball = __ballot(lg == m);
        int bi = __ffsll((unsigned long long)((ball >> grpbase) & 0xffffULL)) - 1;
        psum_acc += p * g;
        cnt_acc += (j == bi) ? 1 : 0;
        if (j == 0) { gate_out[tok] = g; d_idx[tok] = (float)bi; }

        int d0 = j * 8;
        const floatx4* E  = (const floatx4*)(embW + op * 128 + d0);
        const floatx4* A4 = (const floatx4*)(Ta + a * 128 + d0);
        const floatx4* B4 = (const floatx4*)(Tb + b * 128 + d0);
        const floatx4* C4 = (const floatx4*)(Tc + d0);
        floatx4 v0 = E[0] + A4[0] + B4[0] + cf * C4[0];
        floatx4 v1 = E[1] + A4[1] + B4[1] + cf * C4[1];
        uintx4 o;
        o[0] = cvtpk(v0[0], v0[1]);
        o[1] = cvtpk(v0[2], v0[3]);
        o[2] = cvtpk(v1[0], v1[1]);
        o[3] = cvtpk(v1[2], v1[3]);
        *(uintx4*)(xq + (long)tok * 128 + d0) = o;
    }

    psum_acc += __shfl_xor(psum_acc, 16);
    psum_acc += __shfl_xor(psum_acc, 32);
    cnt_acc += __shfl_xor(cnt_acc, 16);
    cnt_acc += __shfl_xor(cnt_acc, 32);
    int wv = threadIdx.x >> 6;
    if (lane < 16) { sp[wv][j] = psum_acc; sc[wv][j] = cnt_acc; }
    __syncthreads();
    if (threadIdx.x < 16) {
        int jj = threadIdx.x;
        atomicAdd(&psum[jj], sp[0][jj] + sp[1][jj] + sp[2][jj] + sp[3][jj]);
        atomicAdd(&cnt[jj], sc[0][jj] + sc[1][jj] + sc[2][jj] + sc[3][jj]);
    }
}

// ---------------- scatter (local prefix from cnt) ----------------

__global__ void k_scatter(const float* __restrict__ d_idx, const int* __restrict__ cnt,
                          int* fill, int* __restrict__ bucket) {
    __shared__ int lc[16], lbase[16];
    if (threadIdx.x < 16) lc[threadIdx.x] = 0;
    __syncthreads();
    int offs[16];
    {
        int off = 0;
        #pragma unroll
        for (int tt = 0; tt < 16; tt++) { offs[tt] = off; off += cnt[tt]; }
    }
    int tok = blockIdx.x * 256 + threadIdx.x;
    int t = (int)d_idx[tok];
    int lpos = atomicAdd(&lc[t], 1);
    __syncthreads();
    if (threadIdx.x < 16) lbase[threadIdx.x] = atomicAdd(&fill[threadIdx.x], lc[threadIdx.x]);
    __syncthreads();
    bucket[offs[t] + lbase[t] + lpos] = tok;
}

// ---------------- Phase C: MoE FFN + fused head ----------------
// GEMM1: P^T = W1 @ X^T (A=W1 rows global, B=Ax LDS) -> gelu -> Pb
// GEMM2': Hpre^T = W23 @ P^T via (A=W23 rows global, B=Pb LDS), accum over chunks
// H = relu(gate*Hpre + bh1) -> head sigmoid(H@Wh2+bh2)

__global__ __launch_bounds__(256, 4) void k_ffn(
    const unsigned short* __restrict__ xq, const float* __restrict__ gate,
    const int* __restrict__ bucket, const int* __restrict__ cnt_g,
    const float* __restrict__ psum_g, const float* __restrict__ ternsum_g,
    const unsigned short* __restrict__ W1qT, const unsigned short* __restrict__ W23qT,
    const float* __restrict__ Wh2, const float* __restrict__ bh1,
    const float* __restrict__ bh2,
    float* __restrict__ result, float* __restrict__ d_aux) {

    extern __shared__ __align__(16) unsigned char smem[];
    unsigned short* Ax = (unsigned short*)smem;            // [64][136] bf16
    unsigned short* Pb = Ax + 64 * 136;                    // [64][136] bf16; later H f32 [64][68]
    int*   toks = (int*)(smem + 34816);
    float* gats = (float*)(smem + 35072);
    float* Wh2l = (float*)(smem + 35328);                  // 512 f
    float* bh2l = (float*)(smem + 37376);                  // 8 f
    float* bh1l = (float*)(smem + 37408);                  // 64 f

    int bid = blockIdx.x;
    // per-block uniform bid -> (tile, chunk) mapping from cnt
    int t = -1, ci = 0, nt = 0, base = 0;
    {
        int coff = 0, off = 0;
        #pragma unroll 1
        for (int tt = 0; tt < 16; tt++) {
            int c = cnt_g[tt];
            int ch = (c + 63) >> 6;
            if (t < 0 && bid < coff + ch) { t = tt; ci = bid - coff; nt = c; base = off + ci * 64; }
            coff += ch; off += c;
        }
    }
    if (t < 0) return;
    int nvalid = nt - ci * 64; if (nvalid > 64) nvalid = 64;

    int tid = threadIdx.x;
    if (tid < 64) {
        int tk = (tid < nvalid) ? bucket[base + tid] : -1;
        toks[tid] = tk;
        gats[tid] = (tk >= 0) ? gate[tk] : 0.0f;
    }
    Wh2l[tid] = Wh2[tid];
    Wh2l[tid + 256] = Wh2[tid + 256];
    if (tid < 8) bh2l[tid] = bh2[tid];
    else if (tid < 72) bh1l[tid - 8] = bh1[tid - 8];
    __syncthreads();

    // stage x rows (gathered, zero-padded)
    #pragma unroll
    for (int it = 0; it < 4; it++) {
        int seg = it * 256 + tid; int r = seg >> 4, sg = seg & 15;
        int tk = toks[r];
        uintx4 v = {0u, 0u, 0u, 0u};
        if (tk >= 0) v = *(const uintx4*)(xq + (long)tk * 128 + sg * 8);
        *(uintx4*)(Ax + r * 136 + sg * 8) = v;
    }
    __syncthreads();

    int lane = tid & 63, dh = tid >> 6;
    int lane15 = lane & 15, lgrp = lane >> 4;

    floatx4 acc3[4];
    #pragma unroll
    for (int j = 0; j < 4; j++) acc3[j] = (floatx4){0.f, 0.f, 0.f, 0.f};

    const unsigned short* w1p = W1qT + (long)t * 65536 + (dh * 32 + lane15) * 128 + lgrp * 8;
    const unsigned short* w23p = W23qT + ((long)t * 64 + dh * 16 + lane15) * 512 + lgrp * 8;

    for (int nc = 0; nc < 4; nc++) {
        // GEMM1: A = W1 rows (global), B = Ax (LDS)
        floatx4 acc1[2][4];
        #pragma unroll
        for (int i = 0; i < 2; i++)
            #pragma unroll
            for (int j = 0; j < 4; j++) acc1[i][j] = (floatx4){0.f, 0.f, 0.f, 0.f};

        const unsigned short* w1c = w1p + nc * 16384;
        #pragma unroll
        for (int kk = 0; kk < 4; kk++) {
            short8 af0 = *(const short8*)(w1c + kk * 32);
            short8 af1 = *(const short8*)(w1c + 2048 + kk * 32);
            int ko = kk * 32 + lgrp * 8;
            #pragma unroll
            for (int mt = 0; mt < 4; mt++) {
                short8 bf = *(const short8*)(Ax + (mt * 16 + lane15) * 136 + ko);
                acc1[0][mt] = mfma16(af0, bf, acc1[0][mt]);
                acc1[1][mt] = mfma16(af1, bf, acc1[1][mt]);
            }
        }
        __syncthreads();                     // prev GEMM2' Pb reads done

        // gelu -> Pb[m][k2local]
        #pragma unroll
        for (int i = 0; i < 2; i++) {
            int k2b = dh * 32 + i * 16 + lgrp * 4;
            #pragma unroll
            for (int mt = 0; mt < 4; mt++) {
                int m = mt * 16 + lane15;
                floatx4 v = acc1[i][mt];
                float g0 = gelu_f(v[0]), g1v = gelu_f(v[1]);
                float g2v = gelu_f(v[2]), g3 = gelu_f(v[3]);
                uintx2 o; o[0] = cvtpk(g0, g1v); o[1] = cvtpk(g2v, g3);
                *(uintx2*)(Pb + m * 136 + k2b) = o;
            }
        }
        __syncthreads();                     // Pb ready

        // GEMM2': A = W23 rows (global), B = Pb (LDS), accum
        const unsigned short* w23c = w23p + nc * 128;
        #pragma unroll
        for (int kk = 0; kk < 4; kk++) {
            short8 af = *(const short8*)(w23c + kk * 32);
            int ko = kk * 32 + lgrp * 8;
            #pragma unroll
            for (int mt = 0; mt < 4; mt++) {
                short8 bf = *(const short8*)(Pb + (mt * 16 + lane15) * 136 + ko);
                acc3[mt] = mfma16(af, bf, acc3[mt]);
            }
        }
    }

    __syncthreads();                         // last GEMM2' reads done; Pb free
    float* H = (float*)Pb;                   // [64 m][68] f32
    int hb = dh * 16 + lgrp * 4;
    floatx4 b4 = *(const floatx4*)(bh1l + hb);
    #pragma unroll
    for (int mt = 0; mt < 4; mt++) {
        int m = mt * 16 + lane15;
        float gm = gats[m];
        floatx4 v;
        v[0] = fmaxf(acc3[mt][0] * gm + b4[0], 0.f);
        v[1] = fmaxf(acc3[mt][1] * gm + b4[1], 0.f);
        v[2] = fmaxf(acc3[mt][2] * gm + b4[2], 0.f);
        v[3] = fmaxf(acc3[mt][3] * gm + b4[3], 0.f);
        *(floatx4*)(H + m * 68 + hb) = v;
    }
    __syncthreads();                         // H complete

    int mloc = tid >> 2, c0 = (tid & 3) * 2;
    int tk = toks[mloc];
    float z0 = bh2l[c0], z1 = bh2l[c0 + 1];
    const floatx4* Hr4 = (const floatx4*)(H + mloc * 68);
    #pragma unroll
    for (int h4 = 0; h4 < 16; h4++) {
        floatx4 hv = Hr4[h4];
        #pragma unroll
        for (int r = 0; r < 4; r++) {
            int h = h4 * 4 + r;
            z0 += hv[r] * Wh2l[h * 8 + c0];
            z1 += hv[r] * Wh2l[h * 8 + c0 + 1];
        }
    }
    if (tk >= 0) {
        float2 rr;
        rr.x = __builtin_amdgcn_rcpf(1.0f + __expf(-z0));
        rr.y = __builtin_amdgcn_rcpf(1.0f + __expf(-z1));
        *(float2*)(result + (long)tk * 8 + c0) = rr;
    }

    // aux loss (block 0 only)
    if (bid == 0 && tid == 0) {
        const float Bf = 262144.0f;
        float tern = ternsum_g[0] * (1.0f / 1048576.0f);
        float sp = 0.f; float cp[4] = {0.f, 0.f, 0.f, 0.f};
        for (int tt = 0; tt < 16; tt++) {
            float frac = (float)cnt_g[tt] / Bf, mp = psum_g[tt] / Bf;
            sp += frac * mp; cp[tt >> 2] += mp;
        }
        float dv = 0.f;
        for (int cc = 0; cc < 4; cc++) dv += cp[cc] * logf(cp[cc] + 1e-9f);
        d_aux[0] = 0.01f * tern + 0.005f * (16.0f * sp) + 0.01f * dv;
    }
}

// ---------------- launch ----------------

extern "C" void kernel_launch(void* const* d_in, const int* in_sizes, int n_in,
                              void* d_out, int out_size, void* d_ws, size_t ws_size,
                              hipStream_t stream) {
    const int* op_idx = (const int*)d_in[0];
    const int* a_in   = (const int*)d_in[1];
    const int* b_in_i = (const int*)d_in[2];
    const int* c_in   = (const int*)d_in[3];
    const float* op_embed = (const float*)d_in[4];
    const float* W_in  = (const float*)d_in[5];
    const float* b_in  = (const float*)d_in[6];
    const float* Wr    = (const float*)d_in[7];
    const float* W1    = (const float*)d_in[8];
    const float* W2    = (const float*)d_in[9];
    const float* Wh1   = (const float*)d_in[10];
    const float* bh1   = (const float*)d_in[11];
    const float* Wh2   = (const float*)d_in[12];
    const float* bh2   = (const float*)d_in[13];

    const long B = in_sizes[0];  // 262144
    float* result = (float*)d_out;
    float* d_idx  = (float*)d_out + B * 8;
    float* d_aux  = (float*)d_out + B * 9;

    unsigned char* ws = (unsigned char*)d_ws;
    unsigned short* xq    = (unsigned short*)(ws + 0);            // 64 MB
    unsigned short* W1qT  = (unsigned short*)(ws + 67108864);     // 2 MB
    unsigned short* W2qT  = (unsigned short*)(ws + 69206016);     // 2 MB
    unsigned short* W23qT = (unsigned short*)(ws + 71303168);     // 1 MB
    float* gate  = (float*)(ws + 72351744);                       // 1 MB
    int*   bucket= (int*)  (ws + 73400320);                       // 1 MB
    float* Ta    = (float*)(ws + 74448896);                       // 128 KB
    float* Tb    = (float*)(ws + 74579968);                       // 128 KB
    float* embW  = (float*)(ws + 74711040);                       // 4 KB
    float* Tc    = (float*)(ws + 74715136);                       // 512 B
    float* TaR   = (float*)(ws + 74715648);                       // 16 KB
    float* TbR   = (float*)(ws + 74732032);                       // 16 KB
    float* embWr = (float*)(ws + 74748416);                       // 512 B
    float* TcR   = (float*)(ws + 74748928);                       // 64 B
    float* partials = (float*)(ws + 74748992);                    // 2 KB
    unsigned char* acc = ws + 74751040;
    float* ternsum = (float*)(acc + 0);
    float* psum    = (float*)(acc + 64);
    int*   cnt     = (int*)(acc + 128);
    int*   fill    = (int*)(acc + 192);

    hipMemsetAsync(acc, 0, 256, stream);

    k_sumabs<<<512, 256, 0, stream>>>(W1, W2, partials);
    k_quant<<<512, 256, 0, stream>>>(W1, W2, partials, W1qT, W2qT, ternsum);
    k_tables<<<261, 256, 0, stream>>>(op_embed, W_in, b_in, embW, Ta, Tb, Tc);
    k_tablesR<<<33, 256, 0, stream>>>(embW, Ta, Tb, Tc, Wr, embWr, TaR, TbR, TcR);
    k_front<<<1024, 256, 0, stream>>>(op_idx, a_in, b_in_i, c_in,
                                      embW, Ta, Tb, Tc, embWr, TaR, TbR, TcR,
                                      xq, gate, psum, cnt, d_idx);
    k_w23<<<1024, 256, 0, stream>>>(W2qT, Wh1, W23qT);
    k_scatter<<<(int)(B / 256), 256, 0, stream>>>(d_idx, cnt, fill, bucket);
    k_ffn<<<4112, 256, 37664, stream>>>(xq, gate, bucket, cnt, psum, ternsum,
                                        W1qT, W23qT, Wh2, bh1, bh2, result, d_aux);
}

// Round 2
// 279.419 us; speedup vs baseline: 1.0364x; 1.0097x over previous
//
#include <hip/hip_runtime.h>
#include <hip/hip_bf16.h>
#include <math.h>

typedef __attribute__((ext_vector_type(8))) short short8;
typedef __attribute__((ext_vector_type(4))) float floatx4;
typedef __attribute__((ext_vector_type(4))) unsigned int uintx4;
typedef __attribute__((ext_vector_type(2))) unsigned int uintx2;

__device__ __forceinline__ unsigned short f2bf(float f) {
    unsigned int u = __float_as_uint(f);
    unsigned int r = (u + 0x7fffu + ((u >> 16) & 1u)) >> 16;
    return (unsigned short)r;
}

// single-instruction RNE pack: low16 <- a, high16 <- b
__device__ __forceinline__ unsigned int cvtpk(float a, float b) {
    unsigned int r;
    asm("v_cvt_pk_bf16_f32 %0, %1, %2" : "=v"(r) : "v"(a), "v"(b));
    return r;
}

// swap a's upper 32 lanes with b's lower 32 lanes
__device__ __forceinline__ void permlane32_swap(unsigned int &a, unsigned int &b) {
    asm volatile("v_permlane32_swap_b32 %0, %1" : "+v"(a), "+v"(b));
}
// swap a's odd 16-lane groups with b's even 16-lane groups
__device__ __forceinline__ void permlane16_swap(unsigned int &a, unsigned int &b) {
    asm volatile("v_permlane16_swap_b32 %0, %1" : "+v"(a), "+v"(b));
}

// gelu(u) = u * sigmoid(1.5957691216*u*(1+0.044715*u^2))
// log2e folded: z = -(k1 + k3*u^2)*u, e = 2^z
__device__ __forceinline__ float gelu_f(float u) {
    float u2 = u * u;
    float p = __builtin_fmaf(u2, -0.102943242f, -2.302208184f);
    float z = p * u;
    float e;
    asm("v_exp_f32 %0, %1" : "=v"(e) : "v"(z));
    return u * __builtin_amdgcn_rcpf(1.0f + e);
}

__device__ __forceinline__ floatx4 mfma16(short8 a, short8 b, floatx4 c) {
    return __builtin_amdgcn_mfma_f32_16x16x32_bf16(a, b, c, 0, 0, 0);
}

// ---------------- Phase A ----------------

// 512 blocks: deterministic partial |W| sums (16 partials per tile)
__global__ __launch_bounds__(256) void k_sumabs(const float* __restrict__ W1,
                                                const float* __restrict__ W2,
                                                float* __restrict__ partials) {
    int blk = blockIdx.x;
    bool isW1 = blk < 256;
    const float* W = (isW1 ? W1 : W2) + (long)(isW1 ? blk : blk - 256) * 4096;
    float s = 0.f;
    #pragma unroll
    for (int i = 0; i < 4; i++) {
        floatx4 v = *(const floatx4*)(W + i * 1024 + threadIdx.x * 4);
        s += fabsf(v[0]) + fabsf(v[1]) + fabsf(v[2]) + fabsf(v[3]);
    }
    __shared__ float red[256];
    red[threadIdx.x] = s; __syncthreads();
    for (int st = 128; st > 0; st >>= 1) {
        if (threadIdx.x < st) red[threadIdx.x] += red[threadIdx.x + st];
        __syncthreads();
    }
    if (threadIdx.x == 0) partials[blk] = red[0];
}

// 512 blocks x 256 threads x 16 elems; deterministic s from partials
__global__ __launch_bounds__(256) void k_quant(
        const float* __restrict__ W1, const float* __restrict__ W2,
        const float* __restrict__ partials,
        unsigned short* __restrict__ W1qT, unsigned short* __restrict__ W2qT,
        float* ternsum) {
    int blk = blockIdx.x;
    bool isW1 = blk < 256;
    long el0 = (long)(isW1 ? blk : blk - 256) * 4096;
    int t = (int)(el0 >> 16);
    const float* part = partials + (isW1 ? 0 : 256) + t * 16;
    float ssum = 0.f;
    #pragma unroll
    for (int i = 0; i < 16; i++) ssum += part[i];
    float s = ssum * (1.0f / 65536.0f);
    float thr = 0.7f * s;
    unsigned int us = (unsigned int)f2bf(s);   // bf16(+s); bf16(-s) = us|0x8000
    const float* Wsrc = (isW1 ? W1 : W2) + el0;
    unsigned short* dst = (isW1 ? W1qT : W2qT) + (long)t * 65536;
    int locbase = (int)(el0 & 65535);
    float dsum = 0.f;
    #pragma unroll
    for (int i = 0; i < 4; i++) {
        int off = i * 1024 + threadIdx.x * 4;
        floatx4 w = *(const floatx4*)(Wsrc + off);
        int loc = locbase + off;
        #pragma unroll
        for (int r = 0; r < 4; r++) {
            float wv = w[r];
            float aw = fabsf(wv);
            bool big = aw > thr;
            dsum += big ? fabsf(aw - s) : aw;
            unsigned int sign15 = (__float_as_uint(wv) >> 16) & 0x8000u;
            unsigned short q = big ? (unsigned short)(us | sign15) : (unsigned short)0;
            int lr = loc + r;
            int addr = isW1 ? ((lr & 511) * 128 + (lr >> 9))
                            : ((lr & 127) * 512 + (lr >> 7));
            dst[addr] = q;
        }
    }
    __shared__ float red[256];
    red[threadIdx.x] = dsum; __syncthreads();
    for (int st2 = 128; st2 > 0; st2 >>= 1) {
        if (threadIdx.x < st2) red[threadIdx.x] += red[threadIdx.x + st2];
        __syncthreads();
    }
    if (threadIdx.x == 0) atomicAdd(ternsum, red[0]);
}

// W23qT[t][h][k2] = (W2q[t] @ Wh1)^T, bf16
__global__ __launch_bounds__(256) void k_w23(
        const unsigned short* __restrict__ W2qT, const float* __restrict__ Wh1,
        unsigned short* __restrict__ W23qT) {
    int t = blockIdx.x >> 6, h = blockIdx.x & 63;
    __shared__ float wcol[128];
    if (threadIdx.x < 128) wcol[threadIdx.x] = Wh1[threadIdx.x * 64 + h];
    __syncthreads();
    int k2 = threadIdx.x * 2;
    const unsigned short* w2 = W2qT + (long)t * 65536 + k2;
    float a0 = 0.f, a1 = 0.f;
    #pragma unroll 8
    for (int d = 0; d < 128; d++) {
        unsigned int u = *(const unsigned int*)(w2 + d * 512);
        float w = wcol[d];
        a0 += w * __uint_as_float(u << 16);
        a1 += w * __uint_as_float(u & 0xffff0000u);
    }
    *(unsigned int*)(W23qT + ((long)(t * 64 + h)) * 512 + k2) = cvtpk(a0, a1);
}

__global__ void k_tables(const float* __restrict__ op_embed, const float* __restrict__ W_in,
                         const float* __restrict__ b_in,
                         float* embW, float* Ta, float* Tb, float* Tc) {
    int i = blockIdx.x * 256 + threadIdx.x;
    if (i < 1024) {
        int op = i >> 7, j = i & 127;
        float s = b_in[j];
        #pragma unroll
        for (int k = 0; k < 32; k++) s += op_embed[op * 32 + k] * W_in[k * 128 + j];
        embW[i] = s;
    } else if (i < 1024 + 32768) {
        int r = i - 1024; int a = r >> 7, j = r & 127;
        float s = 0.f;
        #pragma unroll
        for (int bit = 0; bit < 8; bit++) if ((a >> bit) & 1) s += W_in[(32 + bit) * 128 + j];
        Ta[r] = s;
    } else if (i < 33792 + 32768) {
        int r = i - 33792; int b = r >> 7, j = r & 127;
        float s = 0.f;
        #pragma unroll
        for (int bit = 0; bit < 8; bit++) if ((b >> bit) & 1) s += W_in[(40 + bit) * 128 + j];
        Tb[r] = s;
    } else if (i < 66560 + 128) {
        int j = i - 66560; Tc[j] = W_in[48 * 128 + j];
    }
}

__global__ void k_tablesR(const float* __restrict__ embW, const float* __restrict__ Ta,
                          const float* __restrict__ Tb, const float* __restrict__ Tc,
                          const float* __restrict__ Wr,
                          float* embWr, float* TaR, float* TbR, float* TcR) {
    int i = blockIdx.x * 256 + threadIdx.x;
    int row = i >> 4, t = i & 15;
    const float* src; float* dst;
    if (row < 8)        { src = embW + row * 128;        dst = embWr + i; }
    else if (row < 264) { src = Ta + (row - 8) * 128;    dst = TaR + (row - 8) * 16 + t; }
    else if (row < 520) { src = Tb + (row - 264) * 128;  dst = TbR + (row - 264) * 16 + t; }
    else if (row == 520){ src = Tc;                      dst = TcR + t; }
    else return;
    float s = 0.f;
    for (int j = 0; j < 128; j++) s += src[j] * Wr[j * 16 + t];
    *dst = s;
}

// ---------------- Phase B: router + x ----------------

__global__ __launch_bounds__(256) void k_front(
        const int* __restrict__ op_idx, const int* __restrict__ a_in,
        const int* __restrict__ b_in_i, const int* __restrict__ c_in,
        const float* __restrict__ embW, const float* __restrict__ Ta,
        const float* __restrict__ Tb, const float* __restrict__ Tc,
        const float* __restrict__ embWr, const float* __restrict__ TaR,
        const float* __restrict__ TbR, const float* __restrict__ TcR,
        unsigned short* __restrict__ xq, float* __restrict__ gate_out,
        float* psum, int* cnt, float* __restrict__ d_idx) {
    __shared__ float sp[4][16];
    __shared__ int sc[4][16];
    int gid = blockIdx.x * 256 + threadIdx.x;
    int lane = threadIdx.x & 63;
    int j = lane & 15;
    int grpbase = lane & 48;
    float psum_acc = 0.f; int cnt_acc = 0;

    #pragma unroll 1
    for (int it = 0; it < 16; it++) {
        int tok = it * 16384 + (gid >> 4);
        int op = op_idx[tok], a = a_in[tok], b = b_in_i[tok], c = c_in[tok];
        float cf = (float)c;

        float lg = embWr[op * 16 + j] + TaR[a * 16 + j] + TbR[b * 16 + j] + cf * TcR[j];
        float m = lg;
        m = fmaxf(m, __shfl_xor(m, 8, 16));
        m = fmaxf(m, __shfl_xor(m, 4, 16));
        m = fmaxf(m, __shfl_xor(m, 2, 16));
        m = fmaxf(m, __shfl_xor(m, 1, 16));
        float p = __expf(lg - m);
        float s = p;
        s += __shfl_xor(s, 8, 16);
        s += __shfl_xor(s, 4, 16);
        s += __shfl_xor(s, 2, 16);
        s += __shfl_xor(s, 1, 16);
        float g = __builtin_amdgcn_rcpf(s);
        unsigned long long ball = __ballot(lg == m);
        int bi = __ffsll((unsigned long long)((ball >> grpbase) & 0xffffULL)) - 1;
        psum_acc += p * g;
        cnt_acc += (j == bi) ? 1 : 0;
        if (j == 0) { gate_out[tok] = g; d_idx[tok] = (float)bi; }

        int d0 = j * 8;
        const floatx4* E  = (const floatx4*)(embW + op * 128 + d0);
        const floatx4* A4 = (const floatx4*)(Ta + a * 128 + d0);
        const floatx4* B4 = (const floatx4*)(Tb + b * 128 + d0);
        const floatx4* C4 = (const floatx4*)(Tc + d0);
        floatx4 v0 = E[0] + A4[0] + B4[0] + cf * C4[0];
        floatx4 v1 = E[1] + A4[1] + B4[1] + cf * C4[1];
        uintx4 o;
        o[0] = cvtpk(v0[0], v0[1]);
        o[1] = cvtpk(v0[2], v0[3]);
        o[2] = cvtpk(v1[0], v1[1]);
        o[3] = cvtpk(v1[2], v1[3]);
        *(uintx4*)(xq + (long)tok * 128 + d0) = o;
    }

    psum_acc += __shfl_xor(psum_acc, 16);
    psum_acc += __shfl_xor(psum_acc, 32);
    cnt_acc += __shfl_xor(cnt_acc, 16);
    cnt_acc += __shfl_xor(cnt_acc, 32);
    int wv = threadIdx.x >> 6;
    if (lane < 16) { sp[wv][j] = psum_acc; sc[wv][j] = cnt_acc; }
    __syncthreads();
    if (threadIdx.x < 16) {
        int jj = threadIdx.x;
        atomicAdd(&psum[jj], sp[0][jj] + sp[1][jj] + sp[2][jj] + sp[3][jj]);
        atomicAdd(&cnt[jj], sc[0][jj] + sc[1][jj] + sc[2][jj] + sc[3][jj]);
    }
}

// ---------------- scatter (local prefix from cnt) ----------------

__global__ void k_scatter(const float* __restrict__ d_idx, const int* __restrict__ cnt,
                          int* fill, int* __restrict__ bucket) {
    __shared__ int lc[16], lbase[16];
    if (threadIdx.x < 16) lc[threadIdx.x] = 0;
    __syncthreads();
    int offs[16];
    {
        int off = 0;
        #pragma unroll
        for (int tt = 0; tt < 16; tt++) { offs[tt] = off; off += cnt[tt]; }
    }
    int tok = blockIdx.x * 256 + threadIdx.x;
    int t = (int)d_idx[tok];
    int lpos = atomicAdd(&lc[t], 1);
    __syncthreads();
    if (threadIdx.x < 16) lbase[threadIdx.x] = atomicAdd(&fill[threadIdx.x], lc[threadIdx.x]);
    __syncthreads();
    bucket[offs[t] + lbase[t] + lpos] = tok;
}

// ---------------- Phase C: MoE FFN + fused head ----------------
// GEMM1: P^T = W1 @ X^T (A=W1 rows global, B=Ax LDS) -> gelu -> bf16 in regs
// in-register permute (permlane16/32_swap) builds GEMM2 B-fragments: P never
// touches LDS. GEMM2 (k-split): wave dh owns dff chunk dh*32 of each nc-chunk,
// computes ALL 64 h as partials -> butterfly LDS reduce (lane-linear, no
// conflicts) -> epilogue identical to before. nc loop is barrier-free.

__global__ __launch_bounds__(256, 3) void k_ffn(
    const unsigned short* __restrict__ xq, const float* __restrict__ gate,
    const int* __restrict__ bucket, const int* __restrict__ cnt_g,
    const float* __restrict__ psum_g, const float* __restrict__ ternsum_g,
    const unsigned short* __restrict__ W1qT, const unsigned short* __restrict__ W23qT,
    const float* __restrict__ Wh2, const float* __restrict__ bh1,
    const float* __restrict__ bh2,
    float* __restrict__ result, float* __restrict__ d_aux) {

    extern __shared__ __align__(16) unsigned char smem[];
    unsigned short* Ax = (unsigned short*)smem;            // [64][136] bf16 = 17408 B
    float* Red = (float*)(smem + 17408);                   // 32768 B reduce buf; H [64][68] f32 overlays
    int*   toks = (int*)(smem + 50176);                    // 256 B
    float* gats = (float*)(smem + 50432);                  // 256 B
    float* Wh2l = (float*)(smem + 50688);                  // 2048 B
    float* bh2l = (float*)(smem + 52736);                  // 32 B
    float* bh1l = (float*)(smem + 52768);                  // 256 B  (end 53024)

    int bid = blockIdx.x;
    // per-block uniform bid -> (tile, chunk) mapping from cnt
    int t = -1, ci = 0, nt = 0, base = 0;
    {
        int coff = 0, off = 0;
        #pragma unroll 1
        for (int tt = 0; tt < 16; tt++) {
            int c = cnt_g[tt];
            int ch = (c + 63) >> 6;
            if (t < 0 && bid < coff + ch) { t = tt; ci = bid - coff; nt = c; base = off + ci * 64; }
            coff += ch; off += c;
        }
    }
    if (t < 0) return;
    int nvalid = nt - ci * 64; if (nvalid > 64) nvalid = 64;

    int tid = threadIdx.x;
    if (tid < 64) {
        int tk = (tid < nvalid) ? bucket[base + tid] : -1;
        toks[tid] = tk;
        gats[tid] = (tk >= 0) ? gate[tk] : 0.0f;
    }
    Wh2l[tid] = Wh2[tid];
    Wh2l[tid + 256] = Wh2[tid + 256];
    if (tid < 8) bh2l[tid] = bh2[tid];
    else if (tid < 72) bh1l[tid - 8] = bh1[tid - 8];
    __syncthreads();

    // stage x rows (gathered, zero-padded)
    #pragma unroll
    for (int it = 0; it < 4; it++) {
        int seg = it * 256 + tid; int r = seg >> 4, sg = seg & 15;
        int tk = toks[r];
        uintx4 v = {0u, 0u, 0u, 0u};
        if (tk >= 0) v = *(const uintx4*)(xq + (long)tk * 128 + sg * 8);
        *(uintx4*)(Ax + r * 136 + sg * 8) = v;
    }
    __syncthreads();

    int lane = tid & 63, dh = tid >> 6;
    int lane15 = lane & 15, lgrp = lane >> 4;

    floatx4 acc3[4][4];   // [ht][mt] - ALL h, partial over this wave's dff chunks
    #pragma unroll
    for (int i = 0; i < 4; i++)
        #pragma unroll
        for (int j = 0; j < 4; j++) acc3[i][j] = (floatx4){0.f, 0.f, 0.f, 0.f};

    const unsigned short* w1p  = W1qT + (long)t * 65536 + (dh * 32 + lane15) * 128 + lgrp * 8;
    const unsigned short* w23p = W23qT + ((long)t * 64 + lane15) * 512 + dh * 32 + lgrp * 8;

    for (int nc = 0; nc < 4; nc++) {
        // GEMM1: A = W1 rows (global), B = Ax (LDS)
        floatx4 acc1[2][4];
        #pragma unroll
        for (int i = 0; i < 2; i++)
            #pragma unroll
            for (int j = 0; j < 4; j++) acc1[i][j] = (floatx4){0.f, 0.f, 0.f, 0.f};

        const unsigned short* w1c = w1p + nc * 16384;
        #pragma unroll
        for (int kk = 0; kk < 4; kk++) {
            short8 af0 = *(const short8*)(w1c + kk * 32);
            short8 af1 = *(const short8*)(w1c + 2048 + kk * 32);
            int ko = kk * 32 + lgrp * 8;
            #pragma unroll
            for (int mt = 0; mt < 4; mt++) {
                short8 bf = *(const short8*)(Ax + (mt * 16 + lane15) * 136 + ko);
                acc1[0][mt] = mfma16(af0, bf, acc1[0][mt]);
                acc1[1][mt] = mfma16(af1, bf, acc1[1][mt]);
            }
        }

        // A-fragments for GEMM2 (W23 rows, k = this wave's dff chunk)
        const unsigned short* w23c = w23p + nc * 128;
        short8 af23_0 = *(const short8*)(w23c);
        short8 af23_1 = *(const short8*)(w23c + 8192);
        short8 af23_2 = *(const short8*)(w23c + 16384);
        short8 af23_3 = *(const short8*)(w23c + 24576);

        // fuse: gelu -> cvtpk -> lane permute -> B-fragment -> 4 MFMAs (per mt)
        #pragma unroll
        for (int mt = 0; mt < 4; mt++) {
            floatx4 v0 = acc1[0][mt], v1 = acc1[1][mt];
            unsigned int X0 = cvtpk(gelu_f(v0[0]), gelu_f(v0[1]));   // dff 4g+0,1 (i=0)
            unsigned int X1 = cvtpk(gelu_f(v0[2]), gelu_f(v0[3]));   // dff 4g+2,3
            unsigned int Y0 = cvtpk(gelu_f(v1[0]), gelu_f(v1[1]));   // dff 16+4g+0,1
            unsigned int Y1 = cvtpk(gelu_f(v1[2]), gelu_f(v1[3]));
            permlane32_swap(X0, Y0);   // X0=[x0 x1 y0 y1], Y0=[x2 x3 y2 y3]
            permlane16_swap(X0, Y0);   // X0=[x0 x2 y0 y2]=j0, Y0=[x1 x3 y1 y3]=j2
            permlane32_swap(X1, Y1);
            permlane16_swap(X1, Y1);   // X1=j1, Y1=j3
            union { uintx4 u; short8 s; } bu;
            bu.u[0] = X0; bu.u[1] = X1; bu.u[2] = Y0; bu.u[3] = Y1;
            short8 bfrag = bu.s;
            acc3[0][mt] = mfma16(af23_0, bfrag, acc3[0][mt]);
            acc3[1][mt] = mfma16(af23_1, bfrag, acc3[1][mt]);
            acc3[2][mt] = mfma16(af23_2, bfrag, acc3[2][mt]);
            acc3[3][mt] = mfma16(af23_3, bfrag, acc3[3][mt]);
        }
    }

    // ---- cross-wave k-reduction (butterfly, lane-linear = conflict-free) ----
    bool hi = (dh & 2) != 0;
    floatx4 k0[4], k1[4];
    {
        // stage 1: partner = wave ^ 2. waves 0,1 send ht{2,3}; waves 2,3 send ht{0,1}
        float* mybuf = Red + dh * 2048;
        #pragma unroll
        for (int mt = 0; mt < 4; mt++) {
            floatx4 s0 = hi ? acc3[0][mt] : acc3[2][mt];
            floatx4 s1 = hi ? acc3[1][mt] : acc3[3][mt];
            *(floatx4*)(mybuf + ((0 * 4 + mt) * 64 + lane) * 4) = s0;
            *(floatx4*)(mybuf + ((1 * 4 + mt) * 64 + lane) * 4) = s1;
            k0[mt] = hi ? acc3[2][mt] : acc3[0][mt];
            k1[mt] = hi ? acc3[3][mt] : acc3[1][mt];
        }
        __syncthreads();
        const float* pbuf = Red + (dh ^ 2) * 2048;
        #pragma unroll
        for (int mt = 0; mt < 4; mt++) {
            k0[mt] += *(const floatx4*)(pbuf + ((0 * 4 + mt) * 64 + lane) * 4);
            k1[mt] += *(const floatx4*)(pbuf + ((1 * 4 + mt) * 64 + lane) * 4);
        }
    }
    __syncthreads();
    bool lo1 = (dh & 1) != 0;
    floatx4 fin[4];
    {
        // stage 2: partner = wave ^ 1. final ht = dh.
        float* mybuf = Red + dh * 1024;
        #pragma unroll
        for (int mt = 0; mt < 4; mt++) {
            floatx4 sm = lo1 ? k0[mt] : k1[mt];
            *(floatx4*)(mybuf + (mt * 64 + lane) * 4) = sm;
            fin[mt] = lo1 ? k1[mt] : k0[mt];
        }
        __syncthreads();
        const float* pbuf = Red + (dh ^ 1) * 1024;
        #pragma unroll
        for (int mt = 0; mt < 4; mt++)
            fin[mt] += *(const floatx4*)(pbuf + (mt * 64 + lane) * 4);
    }
    __syncthreads();                         // reduce buffers free; H overlays Red

    float* H = Red;                          // [64 m][68] f32
    int hb = dh * 16 + lgrp * 4;
    floatx4 b4 = *(const floatx4*)(bh1l + hb);
    #pragma unroll
    for (int mt = 0; mt < 4; mt++) {
        int m = mt * 16 + lane15;
        float gm = gats[m];
        floatx4 v;
        v[0] = fmaxf(fin[mt][0] * gm + b4[0], 0.f);
        v[1] = fmaxf(fin[mt][1] * gm + b4[1], 0.f);
        v[2] = fmaxf(fin[mt][2] * gm + b4[2], 0.f);
        v[3] = fmaxf(fin[mt][3] * gm + b4[3], 0.f);
        *(floatx4*)(H + m * 68 + hb) = v;
    }
    __syncthreads();                         // H complete

    int mloc = tid >> 2, c0 = (tid & 3) * 2;
    int tk = toks[mloc];
    float z0 = bh2l[c0], z1 = bh2l[c0 + 1];
    const floatx4* Hr4 = (const floatx4*)(H + mloc * 68);
    #pragma unroll
    for (int h4 = 0; h4 < 16; h4++) {
        floatx4 hv = Hr4[h4];
        #pragma unroll
        for (int r = 0; r < 4; r++) {
            int h = h4 * 4 + r;
            z0 += hv[r] * Wh2l[h * 8 + c0];
            z1 += hv[r] * Wh2l[h * 8 + c0 + 1];
        }
    }
    if (tk >= 0) {
        float2 rr;
        rr.x = __builtin_amdgcn_rcpf(1.0f + __expf(-z0));
        rr.y = __builtin_amdgcn_rcpf(1.0f + __expf(-z1));
        *(float2*)(result + (long)tk * 8 + c0) = rr;
    }

    // aux loss (block 0 only)
    if (bid == 0 && tid == 0) {
        const float Bf = 262144.0f;
        float tern = ternsum_g[0] * (1.0f / 1048576.0f);
        float sp = 0.f; float cp[4] = {0.f, 0.f, 0.f, 0.f};
        for (int tt = 0; tt < 16; tt++) {
            float frac = (float)cnt_g[tt] / Bf, mp = psum_g[tt] / Bf;
            sp += frac * mp; cp[tt >> 2] += mp;
        }
        float dv = 0.f;
        for (int cc = 0; cc < 4; cc++) dv += cp[cc] * logf(cp[cc] + 1e-9f);
        d_aux[0] = 0.01f * tern + 0.005f * (16.0f * sp) + 0.01f * dv;
    }
}

// ---------------- launch ----------------

extern "C" void kernel_launch(void* const* d_in, const int* in_sizes, int n_in,
                              void* d_out, int out_size, void* d_ws, size_t ws_size,
                              hipStream_t stream) {
    const int* op_idx = (const int*)d_in[0];
    const int* a_in   = (const int*)d_in[1];
    const int* b_in_i = (const int*)d_in[2];
    const int* c_in   = (const int*)d_in[3];
    const float* op_embed = (const float*)d_in[4];
    const float* W_in  = (const float*)d_in[5];
    const float* b_in  = (const float*)d_in[6];
    const float* Wr    = (const float*)d_in[7];
    const float* W1    = (const float*)d_in[8];
    const float* W2    = (const float*)d_in[9];
    const float* Wh1   = (const float*)d_in[10];
    const float* bh1   = (const float*)d_in[11];
    const float* Wh2   = (const float*)d_in[12];
    const float* bh2   = (const float*)d_in[13];

    const long B = in_sizes[0];  // 262144
    float* result = (float*)d_out;
    float* d_idx  = (float*)d_out + B * 8;
    float* d_aux  = (float*)d_out + B * 9;

    unsigned char* ws = (unsigned char*)d_ws;
    unsigned short* xq    = (unsigned short*)(ws + 0);            // 64 MB
    unsigned short* W1qT  = (unsigned short*)(ws + 67108864);     // 2 MB
    unsigned short* W2qT  = (unsigned short*)(ws + 69206016);     // 2 MB
    unsigned short* W23qT = (unsigned short*)(ws + 71303168);     // 1 MB
    float* gate  = (float*)(ws + 72351744);                       // 1 MB
    int*   bucket= (int*)  (ws + 73400320);                       // 1 MB
    float* Ta    = (float*)(ws + 74448896);                       // 128 KB
    float* Tb    = (float*)(ws + 74579968);                       // 128 KB
    float* embW  = (float*)(ws + 74711040);                       // 4 KB
    float* Tc    = (float*)(ws + 74715136);                       // 512 B
    float* TaR   = (float*)(ws + 74715648);                       // 16 KB
    float* TbR   = (float*)(ws + 74732032);                       // 16 KB
    float* embWr = (float*)(ws + 74748416);                       // 512 B
    float* TcR   = (float*)(ws + 74748928);                       // 64 B
    float* partials = (float*)(ws + 74748992);                    // 2 KB
    unsigned char* acc = ws + 74751040;
    float* ternsum = (float*)(acc + 0);
    float* psum    = (float*)(acc + 64);
    int*   cnt     = (int*)(acc + 128);
    int*   fill    = (int*)(acc + 192);

    hipMemsetAsync(acc, 0, 256, stream);

    k_sumabs<<<512, 256, 0, stream>>>(W1, W2, partials);
    k_quant<<<512, 256, 0, stream>>>(W1, W2, partials, W1qT, W2qT, ternsum);
    k_tables<<<261, 256, 0, stream>>>(op_embed, W_in, b_in, embW, Ta, Tb, Tc);
    k_tablesR<<<33, 256, 0, stream>>>(embW, Ta, Tb, Tc, Wr, embWr, TaR, TbR, TcR);
    k_front<<<1024, 256, 0, stream>>>(op_idx, a_in, b_in_i, c_in,
                                      embW, Ta, Tb, Tc, embWr, TaR, TbR, TcR,
                                      xq, gate, psum, cnt, d_idx);
    k_w23<<<1024, 256, 0, stream>>>(W2qT, Wh1, W23qT);
    k_scatter<<<(int)(B / 256), 256, 0, stream>>>(d_idx, cnt, fill, bucket);
    k_ffn<<<4112, 256, 53024, stream>>>(xq, gate, bucket, cnt, psum, ternsum,
                                        W1qT, W23qT, Wh2, bh1, bh2, result, d_aux);
}